// Round 9
// baseline (335.574 us; speedup 1.0000x reference)
//
#include <hip/hip_runtime.h>
#include <hip/hip_bf16.h>
#include <stdint.h>

#define B_TOTAL 131072

typedef __attribute__((ext_vector_type(8))) short short8;
typedef __attribute__((ext_vector_type(4))) float float4v;

// ws layout: bf16 region (uint16 indices), then f32 region (float indices)
#define oW1T 0          // [6][128 n][128 kpad] bf16, k>=100 zero
#define oW2T 98304      // [6][64 n][128 k]
#define oW3T 147456     // [6][32 n][64 k]
#define BF16_TOT 159744
#define F32_BASE 79872  // float index
#define oB1 (F32_BASE)        // 768
#define oB2 (F32_BASE+768)    // 384
#define oB3 (F32_BASE+1152)   // 192
#define oW4f (F32_BASE+1344)  // 192
#define oB4 (F32_BASE+1536)   // 6
#define oCP (F32_BASE+1542)   // 36
#define oDC (F32_BASE+1578)   // 6
#define CONV_TOT (BF16_TOT+1584)

__device__ __forceinline__ float bf16_as_f32(uint16_t u) {
    union { uint32_t i; float f; } v; v.i = ((uint32_t)u) << 16; return v.f;
}
__device__ __forceinline__ uint16_t f2bf(float f) {
    uint32_t u = __float_as_uint(f);
    return (uint16_t)((u + 0x7FFFu + ((u >> 16) & 1u)) >> 16);   // RNE
}
__device__ __forceinline__ uint32_t pack2bf(float a, float b) {
    return (uint32_t)f2bf(a) | ((uint32_t)f2bf(b) << 16);
}
__device__ __forceinline__ float sigmoidf_fast(float x) {
    return __builtin_amdgcn_rcpf(1.0f + __expf(-x));
}
__device__ __forceinline__ float siluf(float x) { return x * sigmoidf_fast(x); }

__device__ __forceinline__ float readsrc(const void* p, int off, bool bf) {
    return bf ? bf16_as_f32(((const uint16_t*)p)[off]) : ((const float*)p)[off];
}

// Transposed bf16 weights (k-padded W1) + f32 smalls.  (proven round 8)
__global__ void convert_kernel(const void* W1, const void* b1, const void* W2, const void* b2,
                               const void* W3, const void* b3, const void* W4, const void* b4,
                               const void* cp, const void* dc, uint16_t* __restrict__ wsb) {
    const bool bf = (((const uint32_t*)cp)[0] != 0u);
    int idx = blockIdx.x * 256 + threadIdx.x;
    if (idx >= CONV_TOT) return;
    if (idx < BF16_TOT) {
        float v;
        if (idx < oW2T) {            // W1t[c][n][k(128)] <- W1[c][k][n], k>=100 -> 0
            int c = idx >> 14, r = idx & 16383, n = r >> 7, k = r & 127;
            v = (k < 100) ? readsrc(W1, c * 12800 + k * 128 + n, bf) : 0.0f;
        } else if (idx < oW3T) {     // W2t[c][n(64)][k(128)] <- W2[c][k][n]
            int j = idx - oW2T; int c = j >> 13, r = j & 8191, n = r >> 7, k = r & 127;
            v = readsrc(W2, c * 8192 + k * 64 + n, bf);
        } else {                     // W3t[c][n(32)][k(64)] <- W3[c][k][n]
            int j = idx - oW3T; int c = j >> 11, r = j & 2047, n = r >> 6, k = r & 63;
            v = readsrc(W3, c * 2048 + k * 32 + n, bf);
        }
        wsb[idx] = f2bf(v);
    } else {
        int fi = idx - BF16_TOT;
        float v;
        if      (fi < 768)  v = readsrc(b1, fi, bf);
        else if (fi < 1152) v = readsrc(b2, fi - 768, bf);
        else if (fi < 1344) v = readsrc(b3, fi - 1152, bf);
        else if (fi < 1536) v = readsrc(W4, fi - 1344, bf);
        else if (fi < 1542) v = readsrc(b4, fi - 1536, bf);
        else if (fi < 1578) v = readsrc(cp, fi - 1542, bf);
        else                v = readsrc(dc, fi - 1578, bf);
        ((float*)wsb)[F32_BASE + fi] = v;
    }
}

union Frag { uint4 u4; uint2 u2[2]; uint32_t u[4]; short8 s8; uint16_t h[8]; };

#define SH1_STRIDE 136   // u16; row base 272 B (16B-aligned)
#define SH2_STRIDE 72    // u16; row base 144 B (16B-aligned)

#define MFMA16(A, Bv, acc) acc = __builtin_amdgcn_mfma_f32_16x16x32_bf16((A).s8, (Bv).s8, acc, 0, 0, 0)

// Operand-swapped layout: A = weights (lane: [feature=lm][k=q*8+j]),
// B = activations (lane: [batch=lm][k=q*8+j]).  C/D per lane: batch=lm,
// features = tilebase + q*4 + {0..3}  -> 4 consecutive feature cols
// => packed b64 LDS writes, float4 bias loads, L4 fused into L3 epilogue.
__global__ __launch_bounds__(256, 5)
void chambers_mfma(const void* __restrict__ resv, const uint16_t* __restrict__ wsb,
                   const uint32_t* __restrict__ cpw, float* __restrict__ outF) {
    const float* wsf = (const float*)wsb;
    const bool bfin = (cpw[0] != 0u);
    const int tid = threadIdx.x;
    const int w = tid >> 6, l = tid & 63;
    const int lm = l & 15, q = l >> 4;
    const int rb = blockIdx.x * 64;

    __shared__ uint16_t sH1[64 * SH1_STRIDE];   // 17408 B
    __shared__ uint16_t sH2[64 * SH2_STRIDE];   // 9216 B
    __shared__ float sRawH[6 * 2 * 64];         // 3072 B  (per-half raw partials)

    // ---- preload res B-fragments once (reused by all 6 chambers) ----
    Frag resF[4][4];
#pragma unroll
    for (int rt = 0; rt < 4; ++rt)
#pragma unroll
        for (int kb = 0; kb < 4; ++kb) resF[rt][kb].u4 = make_uint4(0, 0, 0, 0);
    if (bfin) {
#pragma unroll
        for (int rt = 0; rt < 4; ++rt) {
            const uint16_t* bp = (const uint16_t*)resv + (size_t)(rb + rt * 16 + lm) * 100;
#pragma unroll
            for (int kb = 0; kb < 3; ++kb) {
                resF[rt][kb].u2[0] = *(const uint2*)(bp + kb * 32 + q * 8);
                resF[rt][kb].u2[1] = *(const uint2*)(bp + kb * 32 + q * 8 + 4);
            }
            if (q == 0) resF[rt][3].u2[0] = *(const uint2*)(bp + 96);
        }
    } else {
#pragma unroll
        for (int rt = 0; rt < 4; ++rt) {
            const float* fp = (const float*)resv + (size_t)(rb + rt * 16 + lm) * 100;
#pragma unroll
            for (int kb = 0; kb < 3; ++kb) {
                float4 x0 = *(const float4*)(fp + kb * 32 + q * 8);
                float4 x1 = *(const float4*)(fp + kb * 32 + q * 8 + 4);
                resF[rt][kb].u[0] = pack2bf(x0.x, x0.y);
                resF[rt][kb].u[1] = pack2bf(x0.z, x0.w);
                resF[rt][kb].u[2] = pack2bf(x1.x, x1.y);
                resF[rt][kb].u[3] = pack2bf(x1.z, x1.w);
            }
            if (q == 0) {
                float4 x0 = *(const float4*)(fp + 96);
                resF[rt][3].u[0] = pack2bf(x0.x, x0.y);
                resF[rt][3].u[1] = pack2bf(x0.z, x0.w);
            }
        }
    }

#pragma unroll 1
    for (int c = 0; c < 6; ++c) {
        // ===== Layer 1: features as M (8 tiles; wave w -> tiles {2w,2w+1}) =====
        Frag Wa[2][4];
#pragma unroll
        for (int ft = 0; ft < 2; ++ft)
#pragma unroll
            for (int kb = 0; kb < 4; ++kb)
                Wa[ft][kb].u4 = *(const uint4*)(wsb + oW1T + (c * 128 + w * 32 + ft * 16 + lm) * 128 + kb * 32 + q * 8);
        float4 bia0 = *(const float4*)(wsf + oB1 + c * 128 + w * 32 + q * 4);
        float4 bia1 = *(const float4*)(wsf + oB1 + c * 128 + w * 32 + 16 + q * 4);
#pragma unroll
        for (int rt = 0; rt < 4; ++rt) {
            float4v acc0 = {0.f, 0.f, 0.f, 0.f}, acc1 = {0.f, 0.f, 0.f, 0.f};
#pragma unroll
            for (int kb = 0; kb < 4; ++kb) {
                MFMA16(Wa[0][kb], resF[rt][kb], acc0);
                MFMA16(Wa[1][kb], resF[rt][kb], acc1);
            }
            uint16_t* rowp = sH1 + (rt * 16 + lm) * SH1_STRIDE + w * 32 + q * 4;
            uint2 pk;
            pk.x = pack2bf(siluf(acc0[0] + bia0.x), siluf(acc0[1] + bia0.y));
            pk.y = pack2bf(siluf(acc0[2] + bia0.z), siluf(acc0[3] + bia0.w));
            *(uint2*)(void*)rowp = pk;
            pk.x = pack2bf(siluf(acc1[0] + bia1.x), siluf(acc1[1] + bia1.y));
            pk.y = pack2bf(siluf(acc1[2] + bia1.z), siluf(acc1[3] + bia1.w));
            *(uint2*)(void*)(rowp + 16) = pk;
        }
        __syncthreads();

        // ===== Layer 2: features as M (4 tiles; wave w -> tile w) =====
        {
            Frag W2a[4];
#pragma unroll
            for (int kb = 0; kb < 4; ++kb)
                W2a[kb].u4 = *(const uint4*)(wsb + oW2T + (c * 64 + w * 16 + lm) * 128 + kb * 32 + q * 8);
            float4 bia2 = *(const float4*)(wsf + oB2 + c * 64 + w * 16 + q * 4);
#pragma unroll
            for (int rt = 0; rt < 4; ++rt) {
                Frag Hf[4];
#pragma unroll
                for (int kb = 0; kb < 4; ++kb)
                    Hf[kb].u4 = *(const uint4*)(sH1 + (rt * 16 + lm) * SH1_STRIDE + kb * 32 + q * 8);
                float4v acc = {0.f, 0.f, 0.f, 0.f};
#pragma unroll
                for (int kb = 0; kb < 4; ++kb) MFMA16(W2a[kb], Hf[kb], acc);
                uint2 pk;
                pk.x = pack2bf(siluf(acc[0] + bia2.x), siluf(acc[1] + bia2.y));
                pk.y = pack2bf(siluf(acc[2] + bia2.z), siluf(acc[3] + bia2.w));
                *(uint2*)(void*)(sH2 + (rt * 16 + lm) * SH2_STRIDE + w * 16 + q * 4) = pk;
            }
        }
        __syncthreads();

        // ===== Layer 3 + fused L4: wave w -> half ft3=w&1, rows 32*(w>>1)..+31 =====
        {
            const int h = w >> 1, ft3 = w & 1;
            Frag W3a[2];
#pragma unroll
            for (int kb = 0; kb < 2; ++kb)
                W3a[kb].u4 = *(const uint4*)(wsb + oW3T + (c * 32 + ft3 * 16 + lm) * 64 + kb * 32 + q * 8);
            float4 bia3 = *(const float4*)(wsf + oB3 + c * 32 + ft3 * 16 + q * 4);
            float4 w4v  = *(const float4*)(wsf + oW4f + c * 32 + ft3 * 16 + q * 4);
#pragma unroll
            for (int rr = 0; rr < 2; ++rr) {
                const int rt = 2 * h + rr;
                Frag Hf[2];
#pragma unroll
                for (int kb = 0; kb < 2; ++kb)
                    Hf[kb].u4 = *(const uint4*)(sH2 + (rt * 16 + lm) * SH2_STRIDE + kb * 32 + q * 8);
                float4v acc = {0.f, 0.f, 0.f, 0.f};
#pragma unroll
                for (int kb = 0; kb < 2; ++kb) MFMA16(W3a[kb], Hf[kb], acc);
                float p = siluf(acc[0] + bia3.x) * w4v.x + siluf(acc[1] + bia3.y) * w4v.y
                        + siluf(acc[2] + bia3.z) * w4v.z + siluf(acc[3] + bia3.w) * w4v.w;
                p += __shfl_xor(p, 16, 64);
                p += __shfl_xor(p, 32, 64);
                if (q == 0) sRawH[(c * 2 + ft3) * 64 + rt * 16 + lm] = p;
            }
        }
        // no barrier needed here: next L1 writes sH1 (all waves already past the
        // post-L2 barrier); next L2's sH2 writes are fenced by next post-L1 barrier.
    }
    __syncthreads();

    // ===== Coupling fixed point + output =====
    if (tid < 64) {
        float rawv[6], av[6];
#pragma unroll
        for (int c = 0; c < 6; ++c) {
            rawv[c] = sRawH[(c * 2) * 64 + tid] + sRawH[(c * 2 + 1) * 64 + tid] + wsf[oB4 + c];
            av[c] = sigmoidf_fast(rawv[c]);
        }
        const float K = 0.02f;
#pragma unroll 1
        for (int it = 0; it < 5; ++it) {
            float tt[6];
#pragma unroll
            for (int i = 0; i < 6; ++i) tt[i] = av[i] * wsf[oDC + i] * K;
#pragma unroll
            for (int j = 0; j < 6; ++j) {
                float dl = 0.0f;
#pragma unroll
                for (int i = 0; i < 6; ++i) dl = fmaf(tt[i], wsf[oCP + i * 6 + j], dl);
                av[j] = sigmoidf_fast(rawv[j] + dl);
            }
        }
        const int b = rb + tid;
        float2* oa = (float2*)(outF + (size_t)b * 6);
        oa[0] = make_float2(av[0], av[1]);
        oa[1] = make_float2(av[2], av[3]);
        oa[2] = make_float2(av[4], av[5]);
        float2* orw = (float2*)(outF + (size_t)B_TOTAL * 6 + (size_t)b * 6);
        orw[0] = make_float2(rawv[0], rawv[1]);
        orw[1] = make_float2(rawv[2], rawv[3]);
        orw[2] = make_float2(rawv[4], rawv[5]);
    }
}

extern "C" void kernel_launch(void* const* d_in, const int* in_sizes, int n_in,
                              void* d_out, int out_size, void* d_ws, size_t ws_size,
                              hipStream_t stream) {
    uint16_t* wsb = (uint16_t*)d_ws;
    convert_kernel<<<(CONV_TOT + 255) / 256, 256, 0, stream>>>(
        d_in[1], d_in[2], d_in[3], d_in[4], d_in[5], d_in[6], d_in[7], d_in[8],
        d_in[9], d_in[10], wsb);
    chambers_mfma<<<B_TOTAL / 64, 256, 0, stream>>>(
        d_in[0], wsb, (const uint32_t*)d_in[9], (float*)d_out);
}

// Round 10
// 292.781 us; speedup vs baseline: 1.1462x; 1.1462x over previous
//
#include <hip/hip_runtime.h>
#include <hip/hip_bf16.h>
#include <stdint.h>

#define B_TOTAL 131072

typedef __attribute__((ext_vector_type(8))) short short8;
typedef __attribute__((ext_vector_type(4))) float float4v;

// ws layout: bf16 region (uint16 indices), then f32 region (float indices)
#define oW1T 0          // [6][128 n][128 kpad] bf16, k>=100 zero
#define oW2T 98304      // [6][64 n][128 k]
#define oW3T 147456     // [6][32 n][64 k]
#define BF16_TOT 159744
#define F32_BASE 79872  // float index
#define oB1 (F32_BASE)        // 768
#define oB2 (F32_BASE+768)    // 384
#define oB3 (F32_BASE+1152)   // 192
#define oW4f (F32_BASE+1344)  // 192
#define oB4 (F32_BASE+1536)   // 6
#define oCP (F32_BASE+1542)   // 36
#define oDC (F32_BASE+1578)   // 6
#define CONV_TOT (BF16_TOT+1584)

__device__ __forceinline__ float bf16_as_f32(uint16_t u) {
    union { uint32_t i; float f; } v; v.i = ((uint32_t)u) << 16; return v.f;
}
__device__ __forceinline__ uint16_t f2bf(float f) {
    uint32_t u = __float_as_uint(f);
    return (uint16_t)((u + 0x7FFFu + ((u >> 16) & 1u)) >> 16);   // RNE
}
__device__ __forceinline__ uint32_t pack2bf(float a, float b) {
    return (uint32_t)f2bf(a) | ((uint32_t)f2bf(b) << 16);
}
__device__ __forceinline__ float sigmoidf_fast(float x) {
    return __builtin_amdgcn_rcpf(1.0f + __expf(-x));
}
__device__ __forceinline__ float siluf(float x) { return x * sigmoidf_fast(x); }

__device__ __forceinline__ float readsrc(const void* p, int off, bool bf) {
    return bf ? bf16_as_f32(((const uint16_t*)p)[off]) : ((const float*)p)[off];
}

// Transposed bf16 weights (k-padded W1) + f32 smalls.  (proven round 8)
__global__ void convert_kernel(const void* W1, const void* b1, const void* W2, const void* b2,
                               const void* W3, const void* b3, const void* W4, const void* b4,
                               const void* cp, const void* dc, uint16_t* __restrict__ wsb) {
    const bool bf = (((const uint32_t*)cp)[0] != 0u);
    int idx = blockIdx.x * 256 + threadIdx.x;
    if (idx >= CONV_TOT) return;
    if (idx < BF16_TOT) {
        float v;
        if (idx < oW2T) {            // W1t[c][n][k(128)] <- W1[c][k][n], k>=100 -> 0
            int c = idx >> 14, r = idx & 16383, n = r >> 7, k = r & 127;
            v = (k < 100) ? readsrc(W1, c * 12800 + k * 128 + n, bf) : 0.0f;
        } else if (idx < oW3T) {     // W2t[c][n(64)][k(128)] <- W2[c][k][n]
            int j = idx - oW2T; int c = j >> 13, r = j & 8191, n = r >> 7, k = r & 127;
            v = readsrc(W2, c * 8192 + k * 64 + n, bf);
        } else {                     // W3t[c][n(32)][k(64)] <- W3[c][k][n]
            int j = idx - oW3T; int c = j >> 11, r = j & 2047, n = r >> 6, k = r & 63;
            v = readsrc(W3, c * 2048 + k * 32 + n, bf);
        }
        wsb[idx] = f2bf(v);
    } else {
        int fi = idx - BF16_TOT;
        float v;
        if      (fi < 768)  v = readsrc(b1, fi, bf);
        else if (fi < 1152) v = readsrc(b2, fi - 768, bf);
        else if (fi < 1344) v = readsrc(b3, fi - 1152, bf);
        else if (fi < 1536) v = readsrc(W4, fi - 1344, bf);
        else if (fi < 1542) v = readsrc(b4, fi - 1536, bf);
        else if (fi < 1578) v = readsrc(cp, fi - 1542, bf);
        else                v = readsrc(dc, fi - 1578, bf);
        ((float*)wsb)[F32_BASE + fi] = v;
    }
}

union Frag { uint4 u4; uint2 u2[2]; uint32_t u[4]; short8 s8; uint16_t h[8]; };

#define SH1_STRIDE 136   // u16; row base 272 B (16B-aligned)
#define SH2_STRIDE 72    // u16; row base 144 B (16B-aligned)

#define MFMA16(A, Bv, acc) acc = __builtin_amdgcn_mfma_f32_16x16x32_bf16((A).s8, (Bv).s8, acc, 0, 0, 0)

// Operand-swapped layout (round 9, correctness-proven): A = weights
// (lane: [feature=lm][k=q*8+j]), B = activations (lane: [batch=lm][k=q*8+j]).
// C/D per lane: batch=lm, features = tile + q*4 + {0..3}.
// Round-10 fix: NO cross-chamber res register preload (round 9's resF[4][4]
// blew the launch_bounds(256,5) VGPR cap and spilled -> 236 MB scratch writes).
// res is reloaded per chamber per rowtile from global; it stays L1/L2-hot.
__global__ __launch_bounds__(256, 5)
void chambers_mfma(const void* __restrict__ resv, const uint16_t* __restrict__ wsb,
                   const uint32_t* __restrict__ cpw, float* __restrict__ outF) {
    const float* wsf = (const float*)wsb;
    const bool bfin = (cpw[0] != 0u);
    const int tid = threadIdx.x;
    const int w = tid >> 6, l = tid & 63;
    const int lm = l & 15, q = l >> 4;
    const int rb = blockIdx.x * 64;

    __shared__ uint16_t sH1[64 * SH1_STRIDE];   // 17408 B
    __shared__ uint16_t sH2[64 * SH2_STRIDE];   // 9216 B
    __shared__ float sRawH[6 * 2 * 64];         // 3072 B  (per-half raw partials)

#pragma unroll 1
    for (int c = 0; c < 6; ++c) {
        // ===== Layer 1: features as M (8 tiles; wave w -> tiles {2w,2w+1}) =====
        Frag Wa[2][4];
#pragma unroll
        for (int ft = 0; ft < 2; ++ft)
#pragma unroll
            for (int kb = 0; kb < 4; ++kb)
                Wa[ft][kb].u4 = *(const uint4*)(wsb + oW1T + (c * 128 + w * 32 + ft * 16 + lm) * 128 + kb * 32 + q * 8);
        float4 bia0 = *(const float4*)(wsf + oB1 + c * 128 + w * 32 + q * 4);
        float4 bia1 = *(const float4*)(wsf + oB1 + c * 128 + w * 32 + 16 + q * 4);
#pragma unroll
        for (int rt = 0; rt < 4; ++rt) {
            // reload res B-fragment for this rowtile (L1/L2-hot after chamber 0)
            Frag Rf[4];
#pragma unroll
            for (int kb = 0; kb < 4; ++kb) Rf[kb].u4 = make_uint4(0, 0, 0, 0);
            if (bfin) {
                const uint16_t* bp = (const uint16_t*)resv + (size_t)(rb + rt * 16 + lm) * 100;
#pragma unroll
                for (int kb = 0; kb < 3; ++kb) {
                    Rf[kb].u2[0] = *(const uint2*)(bp + kb * 32 + q * 8);
                    Rf[kb].u2[1] = *(const uint2*)(bp + kb * 32 + q * 8 + 4);
                }
                if (q == 0) Rf[3].u2[0] = *(const uint2*)(bp + 96);
            } else {
                const float* fp = (const float*)resv + (size_t)(rb + rt * 16 + lm) * 100;
#pragma unroll
                for (int kb = 0; kb < 3; ++kb) {
                    float4 x0 = *(const float4*)(fp + kb * 32 + q * 8);
                    float4 x1 = *(const float4*)(fp + kb * 32 + q * 8 + 4);
                    Rf[kb].u[0] = pack2bf(x0.x, x0.y);
                    Rf[kb].u[1] = pack2bf(x0.z, x0.w);
                    Rf[kb].u[2] = pack2bf(x1.x, x1.y);
                    Rf[kb].u[3] = pack2bf(x1.z, x1.w);
                }
                if (q == 0) {
                    float4 x0 = *(const float4*)(fp + 96);
                    Rf[3].u[0] = pack2bf(x0.x, x0.y);
                    Rf[3].u[1] = pack2bf(x0.z, x0.w);
                }
            }
            float4v acc0 = {0.f, 0.f, 0.f, 0.f}, acc1 = {0.f, 0.f, 0.f, 0.f};
#pragma unroll
            for (int kb = 0; kb < 4; ++kb) {
                MFMA16(Wa[0][kb], Rf[kb], acc0);
                MFMA16(Wa[1][kb], Rf[kb], acc1);
            }
            uint16_t* rowp = sH1 + (rt * 16 + lm) * SH1_STRIDE + w * 32 + q * 4;
            uint2 pk;
            pk.x = pack2bf(siluf(acc0[0] + bia0.x), siluf(acc0[1] + bia0.y));
            pk.y = pack2bf(siluf(acc0[2] + bia0.z), siluf(acc0[3] + bia0.w));
            *(uint2*)(void*)rowp = pk;
            pk.x = pack2bf(siluf(acc1[0] + bia1.x), siluf(acc1[1] + bia1.y));
            pk.y = pack2bf(siluf(acc1[2] + bia1.z), siluf(acc1[3] + bia1.w));
            *(uint2*)(void*)(rowp + 16) = pk;
        }
        __syncthreads();

        // ===== Layer 2: features as M (4 tiles; wave w -> tile w) =====
        {
            Frag W2a[4];
#pragma unroll
            for (int kb = 0; kb < 4; ++kb)
                W2a[kb].u4 = *(const uint4*)(wsb + oW2T + (c * 64 + w * 16 + lm) * 128 + kb * 32 + q * 8);
            float4 bia2 = *(const float4*)(wsf + oB2 + c * 64 + w * 16 + q * 4);
#pragma unroll
            for (int rt = 0; rt < 4; ++rt) {
                Frag Hf[4];
#pragma unroll
                for (int kb = 0; kb < 4; ++kb)
                    Hf[kb].u4 = *(const uint4*)(sH1 + (rt * 16 + lm) * SH1_STRIDE + kb * 32 + q * 8);
                float4v acc = {0.f, 0.f, 0.f, 0.f};
#pragma unroll
                for (int kb = 0; kb < 4; ++kb) MFMA16(W2a[kb], Hf[kb], acc);
                uint2 pk;
                pk.x = pack2bf(siluf(acc[0] + bia2.x), siluf(acc[1] + bia2.y));
                pk.y = pack2bf(siluf(acc[2] + bia2.z), siluf(acc[3] + bia2.w));
                *(uint2*)(void*)(sH2 + (rt * 16 + lm) * SH2_STRIDE + w * 16 + q * 4) = pk;
            }
        }
        __syncthreads();

        // ===== Layer 3 + fused L4: wave w -> half ft3=w&1, rows 32*(w>>1)..+31 =====
        {
            const int h = w >> 1, ft3 = w & 1;
            Frag W3a[2];
#pragma unroll
            for (int kb = 0; kb < 2; ++kb)
                W3a[kb].u4 = *(const uint4*)(wsb + oW3T + (c * 32 + ft3 * 16 + lm) * 64 + kb * 32 + q * 8);
            float4 bia3 = *(const float4*)(wsf + oB3 + c * 32 + ft3 * 16 + q * 4);
            float4 w4v  = *(const float4*)(wsf + oW4f + c * 32 + ft3 * 16 + q * 4);
#pragma unroll
            for (int rr = 0; rr < 2; ++rr) {
                const int rt = 2 * h + rr;
                Frag Hf[2];
#pragma unroll
                for (int kb = 0; kb < 2; ++kb)
                    Hf[kb].u4 = *(const uint4*)(sH2 + (rt * 16 + lm) * SH2_STRIDE + kb * 32 + q * 8);
                float4v acc = {0.f, 0.f, 0.f, 0.f};
#pragma unroll
                for (int kb = 0; kb < 2; ++kb) MFMA16(W3a[kb], Hf[kb], acc);
                float p = siluf(acc[0] + bia3.x) * w4v.x + siluf(acc[1] + bia3.y) * w4v.y
                        + siluf(acc[2] + bia3.z) * w4v.z + siluf(acc[3] + bia3.w) * w4v.w;
                p += __shfl_xor(p, 16, 64);
                p += __shfl_xor(p, 32, 64);
                if (q == 0) sRawH[(c * 2 + ft3) * 64 + rt * 16 + lm] = p;
            }
        }
        // no barrier: next L1 writes sH1 (distinct from sH2 being read); next L2's
        // sH2 writes are fenced by the next post-L1 barrier.  (proven round 9)
    }
    __syncthreads();

    // ===== Coupling fixed point + output =====
    if (tid < 64) {
        float rawv[6], av[6];
#pragma unroll
        for (int c = 0; c < 6; ++c) {
            rawv[c] = sRawH[(c * 2) * 64 + tid] + sRawH[(c * 2 + 1) * 64 + tid] + wsf[oB4 + c];
            av[c] = sigmoidf_fast(rawv[c]);
        }
        const float K = 0.02f;
#pragma unroll 1
        for (int it = 0; it < 5; ++it) {
            float tt[6];
#pragma unroll
            for (int i = 0; i < 6; ++i) tt[i] = av[i] * wsf[oDC + i] * K;
#pragma unroll
            for (int j = 0; j < 6; ++j) {
                float dl = 0.0f;
#pragma unroll
                for (int i = 0; i < 6; ++i) dl = fmaf(tt[i], wsf[oCP + i * 6 + j], dl);
                av[j] = sigmoidf_fast(rawv[j] + dl);
            }
        }
        const int b = rb + tid;
        float2* oa = (float2*)(outF + (size_t)b * 6);
        oa[0] = make_float2(av[0], av[1]);
        oa[1] = make_float2(av[2], av[3]);
        oa[2] = make_float2(av[4], av[5]);
        float2* orw = (float2*)(outF + (size_t)B_TOTAL * 6 + (size_t)b * 6);
        orw[0] = make_float2(rawv[0], rawv[1]);
        orw[1] = make_float2(rawv[2], rawv[3]);
        orw[2] = make_float2(rawv[4], rawv[5]);
    }
}

extern "C" void kernel_launch(void* const* d_in, const int* in_sizes, int n_in,
                              void* d_out, int out_size, void* d_ws, size_t ws_size,
                              hipStream_t stream) {
    uint16_t* wsb = (uint16_t*)d_ws;
    convert_kernel<<<(CONV_TOT + 255) / 256, 256, 0, stream>>>(
        d_in[1], d_in[2], d_in[3], d_in[4], d_in[5], d_in[6], d_in[7], d_in[8],
        d_in[9], d_in[10], wsb);
    chambers_mfma<<<B_TOTAL / 64, 256, 0, stream>>>(
        d_in[0], wsb, (const uint32_t*)d_in[9], (float*)d_out);
}

// Round 11
// 270.291 us; speedup vs baseline: 1.2415x; 1.0832x over previous
//
#include <hip/hip_runtime.h>
#include <hip/hip_bf16.h>
#include <stdint.h>

#define B_TOTAL 131072

typedef __attribute__((ext_vector_type(8))) short short8;
typedef __attribute__((ext_vector_type(4))) float float4v;

// ws layout: bf16 region (uint16 indices), then f32 region (float indices)
#define oW1T 0          // [6][128 n][128 kpad] bf16, k>=100 zero
#define oW2T 98304      // [6][64 n][128 k]
#define oW3T 147456     // [6][32 n][64 k]
#define BF16_TOT 159744
#define F32_BASE 79872  // float index
#define oB1 (F32_BASE)        // 768
#define oB2 (F32_BASE+768)    // 384
#define oB3 (F32_BASE+1152)   // 192
#define oW4f (F32_BASE+1344)  // 192
#define oB4 (F32_BASE+1536)   // 6
#define oCP (F32_BASE+1542)   // 36
#define oDC (F32_BASE+1578)   // 6
#define CONV_TOT (BF16_TOT+1584)

__device__ __forceinline__ float bf16_as_f32(uint16_t u) {
    union { uint32_t i; float f; } v; v.i = ((uint32_t)u) << 16; return v.f;
}
__device__ __forceinline__ uint16_t f2bf(float f) {
    uint32_t u = __float_as_uint(f);
    return (uint16_t)((u + 0x7FFFu + ((u >> 16) & 1u)) >> 16);   // RNE
}
__device__ __forceinline__ uint32_t pack2bf(float a, float b) {
    return (uint32_t)f2bf(a) | ((uint32_t)f2bf(b) << 16);
}
__device__ __forceinline__ float sigmoidf_fast(float x) {
    return __builtin_amdgcn_rcpf(1.0f + __expf(-x));
}
__device__ __forceinline__ float siluf(float x) { return x * sigmoidf_fast(x); }

__device__ __forceinline__ float readsrc(const void* p, int off, bool bf) {
    return bf ? bf16_as_f32(((const uint16_t*)p)[off]) : ((const float*)p)[off];
}

// Transposed bf16 weights (k-padded W1) + f32 smalls.  (proven round 8)
__global__ void convert_kernel(const void* W1, const void* b1, const void* W2, const void* b2,
                               const void* W3, const void* b3, const void* W4, const void* b4,
                               const void* cp, const void* dc, uint16_t* __restrict__ wsb) {
    const bool bf = (((const uint32_t*)cp)[0] != 0u);
    int idx = blockIdx.x * 256 + threadIdx.x;
    if (idx >= CONV_TOT) return;
    if (idx < BF16_TOT) {
        float v;
        if (idx < oW2T) {            // W1t[c][n][k(128)] <- W1[c][k][n], k>=100 -> 0
            int c = idx >> 14, r = idx & 16383, n = r >> 7, k = r & 127;
            v = (k < 100) ? readsrc(W1, c * 12800 + k * 128 + n, bf) : 0.0f;
        } else if (idx < oW3T) {     // W2t[c][n(64)][k(128)] <- W2[c][k][n]
            int j = idx - oW2T; int c = j >> 13, r = j & 8191, n = r >> 7, k = r & 127;
            v = readsrc(W2, c * 8192 + k * 64 + n, bf);
        } else {                     // W3t[c][n(32)][k(64)] <- W3[c][k][n]
            int j = idx - oW3T; int c = j >> 11, r = j & 2047, n = r >> 6, k = r & 63;
            v = readsrc(W3, c * 2048 + k * 32 + n, bf);
        }
        wsb[idx] = f2bf(v);
    } else {
        int fi = idx - BF16_TOT;
        float v;
        if      (fi < 768)  v = readsrc(b1, fi, bf);
        else if (fi < 1152) v = readsrc(b2, fi - 768, bf);
        else if (fi < 1344) v = readsrc(b3, fi - 1152, bf);
        else if (fi < 1536) v = readsrc(W4, fi - 1344, bf);
        else if (fi < 1542) v = readsrc(b4, fi - 1536, bf);
        else if (fi < 1578) v = readsrc(cp, fi - 1542, bf);
        else                v = readsrc(dc, fi - 1578, bf);
        ((float*)wsb)[F32_BASE + fi] = v;
    }
}

union Frag { uint4 u4; uint2 u2[2]; uint32_t u[4]; short8 s8; uint16_t h[8]; };

#define SH1_STRIDE 136   // u16; row base 272 B (16B-aligned)
#define SH2_STRIDE 72    // u16; row base 144 B (16B-aligned)

#define MFMA16(A, Bv, acc) acc = __builtin_amdgcn_mfma_f32_16x16x32_bf16((A).s8, (Bv).s8, acc, 0, 0, 0)

// Operand-swapped layout (round 9/10, correctness-proven): A = weights
// (lane: [feature=lm][k=q*8+j]), B = activations (lane: [batch=lm][k=q*8+j]).
// C/D per lane: batch=lm, features = tile + q*4 + {0..3}.
// CRITICAL (rounds 9/10 lesson): the rowtile loops with global/LDS fragment
// loads MUST be '#pragma unroll 1'. Full unroll hoists 4 iterations of loads,
// blows the launch_bounds(256,5) VGPR cap (~96) and spills 66+ MiB to scratch
// (round 10: WRITE_SIZE 73.7 MB, FETCH 169 MB, dur +25%).
__global__ __launch_bounds__(256, 5)
void chambers_mfma(const void* __restrict__ resv, const uint16_t* __restrict__ wsb,
                   const uint32_t* __restrict__ cpw, float* __restrict__ outF) {
    const float* wsf = (const float*)wsb;
    const bool bfin = (cpw[0] != 0u);
    const int tid = threadIdx.x;
    const int w = tid >> 6, l = tid & 63;
    const int lm = l & 15, q = l >> 4;
    const int rb = blockIdx.x * 64;

    __shared__ uint16_t sH1[64 * SH1_STRIDE];   // 17408 B
    __shared__ uint16_t sH2[64 * SH2_STRIDE];   // 9216 B
    __shared__ float sRawH[6 * 2 * 64];         // 3072 B  (per-half raw partials)

#pragma unroll 1
    for (int c = 0; c < 6; ++c) {
        // ===== Layer 1: features as M (8 tiles; wave w -> tiles {2w,2w+1}) =====
        Frag Wa[2][4];
#pragma unroll
        for (int ft = 0; ft < 2; ++ft)
#pragma unroll
            for (int kb = 0; kb < 4; ++kb)
                Wa[ft][kb].u4 = *(const uint4*)(wsb + oW1T + (c * 128 + w * 32 + ft * 16 + lm) * 128 + kb * 32 + q * 8);
        float4 bia0 = *(const float4*)(wsf + oB1 + c * 128 + w * 32 + q * 4);
        float4 bia1 = *(const float4*)(wsf + oB1 + c * 128 + w * 32 + 16 + q * 4);
#pragma unroll 1
        for (int rt = 0; rt < 4; ++rt) {
            // reload res B-fragment for this rowtile (L1/L2-hot after chamber 0)
            Frag Rf[4];
#pragma unroll
            for (int kb = 0; kb < 4; ++kb) Rf[kb].u4 = make_uint4(0, 0, 0, 0);
            if (bfin) {
                const uint16_t* bp = (const uint16_t*)resv + (size_t)(rb + rt * 16 + lm) * 100;
#pragma unroll
                for (int kb = 0; kb < 3; ++kb) {
                    Rf[kb].u2[0] = *(const uint2*)(bp + kb * 32 + q * 8);
                    Rf[kb].u2[1] = *(const uint2*)(bp + kb * 32 + q * 8 + 4);
                }
                if (q == 0) Rf[3].u2[0] = *(const uint2*)(bp + 96);
            } else {
                const float* fp = (const float*)resv + (size_t)(rb + rt * 16 + lm) * 100;
#pragma unroll
                for (int kb = 0; kb < 3; ++kb) {
                    float4 x0 = *(const float4*)(fp + kb * 32 + q * 8);
                    float4 x1 = *(const float4*)(fp + kb * 32 + q * 8 + 4);
                    Rf[kb].u[0] = pack2bf(x0.x, x0.y);
                    Rf[kb].u[1] = pack2bf(x0.z, x0.w);
                    Rf[kb].u[2] = pack2bf(x1.x, x1.y);
                    Rf[kb].u[3] = pack2bf(x1.z, x1.w);
                }
                if (q == 0) {
                    float4 x0 = *(const float4*)(fp + 96);
                    Rf[3].u[0] = pack2bf(x0.x, x0.y);
                    Rf[3].u[1] = pack2bf(x0.z, x0.w);
                }
            }
            float4v acc0 = {0.f, 0.f, 0.f, 0.f}, acc1 = {0.f, 0.f, 0.f, 0.f};
#pragma unroll
            for (int kb = 0; kb < 4; ++kb) {
                MFMA16(Wa[0][kb], Rf[kb], acc0);
                MFMA16(Wa[1][kb], Rf[kb], acc1);
            }
            uint16_t* rowp = sH1 + (rt * 16 + lm) * SH1_STRIDE + w * 32 + q * 4;
            uint2 pk;
            pk.x = pack2bf(siluf(acc0[0] + bia0.x), siluf(acc0[1] + bia0.y));
            pk.y = pack2bf(siluf(acc0[2] + bia0.z), siluf(acc0[3] + bia0.w));
            *(uint2*)(void*)rowp = pk;
            pk.x = pack2bf(siluf(acc1[0] + bia1.x), siluf(acc1[1] + bia1.y));
            pk.y = pack2bf(siluf(acc1[2] + bia1.z), siluf(acc1[3] + bia1.w));
            *(uint2*)(void*)(rowp + 16) = pk;
        }
        __syncthreads();

        // ===== Layer 2: features as M (4 tiles; wave w -> tile w) =====
        {
            Frag W2a[4];
#pragma unroll
            for (int kb = 0; kb < 4; ++kb)
                W2a[kb].u4 = *(const uint4*)(wsb + oW2T + (c * 64 + w * 16 + lm) * 128 + kb * 32 + q * 8);
            float4 bia2 = *(const float4*)(wsf + oB2 + c * 64 + w * 16 + q * 4);
#pragma unroll 1
            for (int rt = 0; rt < 4; ++rt) {
                Frag Hf[4];
#pragma unroll
                for (int kb = 0; kb < 4; ++kb)
                    Hf[kb].u4 = *(const uint4*)(sH1 + (rt * 16 + lm) * SH1_STRIDE + kb * 32 + q * 8);
                float4v acc = {0.f, 0.f, 0.f, 0.f};
#pragma unroll
                for (int kb = 0; kb < 4; ++kb) MFMA16(W2a[kb], Hf[kb], acc);
                uint2 pk;
                pk.x = pack2bf(siluf(acc[0] + bia2.x), siluf(acc[1] + bia2.y));
                pk.y = pack2bf(siluf(acc[2] + bia2.z), siluf(acc[3] + bia2.w));
                *(uint2*)(void*)(sH2 + (rt * 16 + lm) * SH2_STRIDE + w * 16 + q * 4) = pk;
            }
        }
        __syncthreads();

        // ===== Layer 3 + fused L4: wave w -> half ft3=w&1, rows 32*(w>>1)..+31 =====
        {
            const int h = w >> 1, ft3 = w & 1;
            Frag W3a[2];
#pragma unroll
            for (int kb = 0; kb < 2; ++kb)
                W3a[kb].u4 = *(const uint4*)(wsb + oW3T + (c * 32 + ft3 * 16 + lm) * 64 + kb * 32 + q * 8);
            float4 bia3 = *(const float4*)(wsf + oB3 + c * 32 + ft3 * 16 + q * 4);
            float4 w4v  = *(const float4*)(wsf + oW4f + c * 32 + ft3 * 16 + q * 4);
#pragma unroll
            for (int rr = 0; rr < 2; ++rr) {
                const int rt = 2 * h + rr;
                Frag Hf[2];
#pragma unroll
                for (int kb = 0; kb < 2; ++kb)
                    Hf[kb].u4 = *(const uint4*)(sH2 + (rt * 16 + lm) * SH2_STRIDE + kb * 32 + q * 8);
                float4v acc = {0.f, 0.f, 0.f, 0.f};
#pragma unroll
                for (int kb = 0; kb < 2; ++kb) MFMA16(W3a[kb], Hf[kb], acc);
                float p = siluf(acc[0] + bia3.x) * w4v.x + siluf(acc[1] + bia3.y) * w4v.y
                        + siluf(acc[2] + bia3.z) * w4v.z + siluf(acc[3] + bia3.w) * w4v.w;
                p += __shfl_xor(p, 16, 64);
                p += __shfl_xor(p, 32, 64);
                if (q == 0) sRawH[(c * 2 + ft3) * 64 + rt * 16 + lm] = p;
            }
        }
        // no barrier: next L1 writes sH1 (sH2 readers already past post-L1 barrier
        // of next chamber before sH2 is rewritten).  (proven rounds 9/10)
    }
    __syncthreads();

    // ===== Coupling fixed point + output =====
    if (tid < 64) {
        float rawv[6], av[6];
#pragma unroll
        for (int c = 0; c < 6; ++c) {
            rawv[c] = sRawH[(c * 2) * 64 + tid] + sRawH[(c * 2 + 1) * 64 + tid] + wsf[oB4 + c];
            av[c] = sigmoidf_fast(rawv[c]);
        }
        const float K = 0.02f;
#pragma unroll 1
        for (int it = 0; it < 5; ++it) {
            float tt[6];
#pragma unroll
            for (int i = 0; i < 6; ++i) tt[i] = av[i] * wsf[oDC + i] * K;
#pragma unroll
            for (int j = 0; j < 6; ++j) {
                float dl = 0.0f;
#pragma unroll
                for (int i = 0; i < 6; ++i) dl = fmaf(tt[i], wsf[oCP + i * 6 + j], dl);
                av[j] = sigmoidf_fast(rawv[j] + dl);
            }
        }
        const int b = rb + tid;
        float2* oa = (float2*)(outF + (size_t)b * 6);
        oa[0] = make_float2(av[0], av[1]);
        oa[1] = make_float2(av[2], av[3]);
        oa[2] = make_float2(av[4], av[5]);
        float2* orw = (float2*)(outF + (size_t)B_TOTAL * 6 + (size_t)b * 6);
        orw[0] = make_float2(rawv[0], rawv[1]);
        orw[1] = make_float2(rawv[2], rawv[3]);
        orw[2] = make_float2(rawv[4], rawv[5]);
    }
}

extern "C" void kernel_launch(void* const* d_in, const int* in_sizes, int n_in,
                              void* d_out, int out_size, void* d_ws, size_t ws_size,
                              hipStream_t stream) {
    uint16_t* wsb = (uint16_t*)d_ws;
    convert_kernel<<<(CONV_TOT + 255) / 256, 256, 0, stream>>>(
        d_in[1], d_in[2], d_in[3], d_in[4], d_in[5], d_in[6], d_in[7], d_in[8],
        d_in[9], d_in[10], wsb);
    chambers_mfma<<<B_TOTAL / 64, 256, 0, stream>>>(
        d_in[0], wsb, (const uint32_t*)d_in[9], (float*)d_out);
}

// Round 12
// 253.680 us; speedup vs baseline: 1.3228x; 1.0655x over previous
//
#include <hip/hip_runtime.h>
#include <hip/hip_bf16.h>
#include <stdint.h>

#define B_TOTAL 131072

typedef __attribute__((ext_vector_type(8))) short short8;
typedef __attribute__((ext_vector_type(4))) float float4v;

// ws layout: bf16 region (uint16 indices), then f32 region (float indices)
#define oW1T 0          // [6][128 n][128 kpad] bf16, k>=100 zero
#define oW2T 98304      // [6][64 n][128 k]
#define oW3T 147456     // [6][32 n][64 k]
#define BF16_TOT 159744
#define F32_BASE 79872  // float index
#define oB1 (F32_BASE)        // 768
#define oB2 (F32_BASE+768)    // 384
#define oB3 (F32_BASE+1152)   // 192
#define oW4f (F32_BASE+1344)  // 192
#define oB4 (F32_BASE+1536)   // 6
#define oCP (F32_BASE+1542)   // 36
#define oDC (F32_BASE+1578)   // 6
#define CONV_TOT (BF16_TOT+1584)

__device__ __forceinline__ float bf16_as_f32(uint16_t u) {
    union { uint32_t i; float f; } v; v.i = ((uint32_t)u) << 16; return v.f;
}
__device__ __forceinline__ uint16_t f2bf(float f) {
    uint32_t u = __float_as_uint(f);
    return (uint16_t)((u + 0x7FFFu + ((u >> 16) & 1u)) >> 16);   // RNE
}
__device__ __forceinline__ uint32_t pack2bf(float a, float b) {
    return (uint32_t)f2bf(a) | ((uint32_t)f2bf(b) << 16);
}
__device__ __forceinline__ float sigmoidf_fast(float x) {
    return __builtin_amdgcn_rcpf(1.0f + __expf(-x));
}
__device__ __forceinline__ float siluf(float x) { return x * sigmoidf_fast(x); }

__device__ __forceinline__ float readsrc(const void* p, int off, bool bf) {
    return bf ? bf16_as_f32(((const uint16_t*)p)[off]) : ((const float*)p)[off];
}

// Transposed bf16 weights (k-padded W1) + f32 smalls.  (proven round 8)
__global__ void convert_kernel(const void* W1, const void* b1, const void* W2, const void* b2,
                               const void* W3, const void* b3, const void* W4, const void* b4,
                               const void* cp, const void* dc, uint16_t* __restrict__ wsb) {
    const bool bf = (((const uint32_t*)cp)[0] != 0u);
    int idx = blockIdx.x * 256 + threadIdx.x;
    if (idx >= CONV_TOT) return;
    if (idx < BF16_TOT) {
        float v;
        if (idx < oW2T) {            // W1t[c][n][k(128)] <- W1[c][k][n], k>=100 -> 0
            int c = idx >> 14, r = idx & 16383, n = r >> 7, k = r & 127;
            v = (k < 100) ? readsrc(W1, c * 12800 + k * 128 + n, bf) : 0.0f;
        } else if (idx < oW3T) {     // W2t[c][n(64)][k(128)] <- W2[c][k][n]
            int j = idx - oW2T; int c = j >> 13, r = j & 8191, n = r >> 7, k = r & 127;
            v = readsrc(W2, c * 8192 + k * 64 + n, bf);
        } else {                     // W3t[c][n(32)][k(64)] <- W3[c][k][n]
            int j = idx - oW3T; int c = j >> 11, r = j & 2047, n = r >> 6, k = r & 63;
            v = readsrc(W3, c * 2048 + k * 32 + n, bf);
        }
        wsb[idx] = f2bf(v);
    } else {
        int fi = idx - BF16_TOT;
        float v;
        if      (fi < 768)  v = readsrc(b1, fi, bf);
        else if (fi < 1152) v = readsrc(b2, fi - 768, bf);
        else if (fi < 1344) v = readsrc(b3, fi - 1152, bf);
        else if (fi < 1536) v = readsrc(W4, fi - 1344, bf);
        else if (fi < 1542) v = readsrc(b4, fi - 1536, bf);
        else if (fi < 1578) v = readsrc(cp, fi - 1542, bf);
        else                v = readsrc(dc, fi - 1578, bf);
        ((float*)wsb)[F32_BASE + fi] = v;
    }
}

union Frag { uint4 u4; uint2 u2[2]; uint32_t u[4]; short8 s8; uint16_t h[8]; };

#define SH1_STRIDE 136   // u16; row base 272 B (16B-aligned)
#define SH2_STRIDE 72    // u16; row base 144 B (16B-aligned)

#define MFMA16(A, Bv, acc) acc = __builtin_amdgcn_mfma_f32_16x16x32_bf16((A).s8, (Bv).s8, acc, 0, 0, 0)

// Operand-swapped layout (rounds 9-11, correctness-proven): A = weights
// (lane: [feature=lm][k=q*8+j]), B = activations (lane: [batch=lm][k=q*8+j]).
// C/D per lane: batch=lm, features = tile + q*4 + {0..3}.
// REGISTER BUDGET (round 11 lesson): launch_bounds(256,5) -> ~102 VGPR cap was
// too tight for the fused L3+L4 + cross-chamber overlap live set -> ~20 MB
// scratch writes + 95 MB re-reads (WRITE 26.6 MB, FETCH 146 MB). (256,4) gives
// 128 VGPRs; LDS still allows 5 blocks/CU, VGPR now allows 4 -> 16 waves/CU,
// above the ~14.6 measured anyway. Rowtile loops stay '#pragma unroll 1'.
__global__ __launch_bounds__(256, 4)
void chambers_mfma(const void* __restrict__ resv, const uint16_t* __restrict__ wsb,
                   const uint32_t* __restrict__ cpw, float* __restrict__ outF) {
    const float* wsf = (const float*)wsb;
    const bool bfin = (cpw[0] != 0u);
    const int tid = threadIdx.x;
    const int w = tid >> 6, l = tid & 63;
    const int lm = l & 15, q = l >> 4;
    const int rb = blockIdx.x * 64;

    __shared__ uint16_t sH1[64 * SH1_STRIDE];   // 17408 B
    __shared__ uint16_t sH2[64 * SH2_STRIDE];   // 9216 B
    __shared__ float sRawH[6 * 2 * 64];         // 3072 B  (per-half raw partials)

#pragma unroll 1
    for (int c = 0; c < 6; ++c) {
        // ===== Layer 1: features as M (8 tiles; wave w -> tiles {2w,2w+1}) =====
        Frag Wa[2][4];
#pragma unroll
        for (int ft = 0; ft < 2; ++ft)
#pragma unroll
            for (int kb = 0; kb < 4; ++kb)
                Wa[ft][kb].u4 = *(const uint4*)(wsb + oW1T + (c * 128 + w * 32 + ft * 16 + lm) * 128 + kb * 32 + q * 8);
        float4 bia0 = *(const float4*)(wsf + oB1 + c * 128 + w * 32 + q * 4);
        float4 bia1 = *(const float4*)(wsf + oB1 + c * 128 + w * 32 + 16 + q * 4);
#pragma unroll 1
        for (int rt = 0; rt < 4; ++rt) {
            // reload res B-fragment for this rowtile (L1/L2-hot after chamber 0)
            Frag Rf[4];
#pragma unroll
            for (int kb = 0; kb < 4; ++kb) Rf[kb].u4 = make_uint4(0, 0, 0, 0);
            if (bfin) {
                const uint16_t* bp = (const uint16_t*)resv + (size_t)(rb + rt * 16 + lm) * 100;
#pragma unroll
                for (int kb = 0; kb < 3; ++kb) {
                    Rf[kb].u2[0] = *(const uint2*)(bp + kb * 32 + q * 8);
                    Rf[kb].u2[1] = *(const uint2*)(bp + kb * 32 + q * 8 + 4);
                }
                if (q == 0) Rf[3].u2[0] = *(const uint2*)(bp + 96);
            } else {
                const float* fp = (const float*)resv + (size_t)(rb + rt * 16 + lm) * 100;
#pragma unroll
                for (int kb = 0; kb < 3; ++kb) {
                    float4 x0 = *(const float4*)(fp + kb * 32 + q * 8);
                    float4 x1 = *(const float4*)(fp + kb * 32 + q * 8 + 4);
                    Rf[kb].u[0] = pack2bf(x0.x, x0.y);
                    Rf[kb].u[1] = pack2bf(x0.z, x0.w);
                    Rf[kb].u[2] = pack2bf(x1.x, x1.y);
                    Rf[kb].u[3] = pack2bf(x1.z, x1.w);
                }
                if (q == 0) {
                    float4 x0 = *(const float4*)(fp + 96);
                    Rf[3].u[0] = pack2bf(x0.x, x0.y);
                    Rf[3].u[1] = pack2bf(x0.z, x0.w);
                }
            }
            float4v acc0 = {0.f, 0.f, 0.f, 0.f}, acc1 = {0.f, 0.f, 0.f, 0.f};
#pragma unroll
            for (int kb = 0; kb < 4; ++kb) {
                MFMA16(Wa[0][kb], Rf[kb], acc0);
                MFMA16(Wa[1][kb], Rf[kb], acc1);
            }
            uint16_t* rowp = sH1 + (rt * 16 + lm) * SH1_STRIDE + w * 32 + q * 4;
            uint2 pk;
            pk.x = pack2bf(siluf(acc0[0] + bia0.x), siluf(acc0[1] + bia0.y));
            pk.y = pack2bf(siluf(acc0[2] + bia0.z), siluf(acc0[3] + bia0.w));
            *(uint2*)(void*)rowp = pk;
            pk.x = pack2bf(siluf(acc1[0] + bia1.x), siluf(acc1[1] + bia1.y));
            pk.y = pack2bf(siluf(acc1[2] + bia1.z), siluf(acc1[3] + bia1.w));
            *(uint2*)(void*)(rowp + 16) = pk;
        }
        __syncthreads();

        // ===== Layer 2: features as M (4 tiles; wave w -> tile w) =====
        {
            Frag W2a[4];
#pragma unroll
            for (int kb = 0; kb < 4; ++kb)
                W2a[kb].u4 = *(const uint4*)(wsb + oW2T + (c * 64 + w * 16 + lm) * 128 + kb * 32 + q * 8);
            float4 bia2 = *(const float4*)(wsf + oB2 + c * 64 + w * 16 + q * 4);
#pragma unroll 1
            for (int rt = 0; rt < 4; ++rt) {
                Frag Hf[4];
#pragma unroll
                for (int kb = 0; kb < 4; ++kb)
                    Hf[kb].u4 = *(const uint4*)(sH1 + (rt * 16 + lm) * SH1_STRIDE + kb * 32 + q * 8);
                float4v acc = {0.f, 0.f, 0.f, 0.f};
#pragma unroll
                for (int kb = 0; kb < 4; ++kb) MFMA16(W2a[kb], Hf[kb], acc);
                uint2 pk;
                pk.x = pack2bf(siluf(acc[0] + bia2.x), siluf(acc[1] + bia2.y));
                pk.y = pack2bf(siluf(acc[2] + bia2.z), siluf(acc[3] + bia2.w));
                *(uint2*)(void*)(sH2 + (rt * 16 + lm) * SH2_STRIDE + w * 16 + q * 4) = pk;
            }
        }
        __syncthreads();

        // ===== Layer 3 + fused L4: wave w -> half ft3=w&1, rows 32*(w>>1)..+31 =====
        {
            const int h = w >> 1, ft3 = w & 1;
            Frag W3a[2];
#pragma unroll
            for (int kb = 0; kb < 2; ++kb)
                W3a[kb].u4 = *(const uint4*)(wsb + oW3T + (c * 32 + ft3 * 16 + lm) * 64 + kb * 32 + q * 8);
            float4 bia3 = *(const float4*)(wsf + oB3 + c * 32 + ft3 * 16 + q * 4);
            float4 w4v  = *(const float4*)(wsf + oW4f + c * 32 + ft3 * 16 + q * 4);
#pragma unroll
            for (int rr = 0; rr < 2; ++rr) {
                const int rt = 2 * h + rr;
                Frag Hf[2];
#pragma unroll
                for (int kb = 0; kb < 2; ++kb)
                    Hf[kb].u4 = *(const uint4*)(sH2 + (rt * 16 + lm) * SH2_STRIDE + kb * 32 + q * 8);
                float4v acc = {0.f, 0.f, 0.f, 0.f};
#pragma unroll
                for (int kb = 0; kb < 2; ++kb) MFMA16(W3a[kb], Hf[kb], acc);
                float p = siluf(acc[0] + bia3.x) * w4v.x + siluf(acc[1] + bia3.y) * w4v.y
                        + siluf(acc[2] + bia3.z) * w4v.z + siluf(acc[3] + bia3.w) * w4v.w;
                p += __shfl_xor(p, 16, 64);
                p += __shfl_xor(p, 32, 64);
                if (q == 0) sRawH[(c * 2 + ft3) * 64 + rt * 16 + lm] = p;
            }
        }
        // no barrier: next L1 writes sH1; next chamber's sH2 writes are fenced by
        // its post-L1 barrier.  (proven rounds 9-11)
    }
    __syncthreads();

    // ===== Coupling fixed point + output =====
    if (tid < 64) {
        float rawv[6], av[6];
#pragma unroll
        for (int c = 0; c < 6; ++c) {
            rawv[c] = sRawH[(c * 2) * 64 + tid] + sRawH[(c * 2 + 1) * 64 + tid] + wsf[oB4 + c];
            av[c] = sigmoidf_fast(rawv[c]);
        }
        const float K = 0.02f;
#pragma unroll 1
        for (int it = 0; it < 5; ++it) {
            float tt[6];
#pragma unroll
            for (int i = 0; i < 6; ++i) tt[i] = av[i] * wsf[oDC + i] * K;
#pragma unroll
            for (int j = 0; j < 6; ++j) {
                float dl = 0.0f;
#pragma unroll
                for (int i = 0; i < 6; ++i) dl = fmaf(tt[i], wsf[oCP + i * 6 + j], dl);
                av[j] = sigmoidf_fast(rawv[j] + dl);
            }
        }
        const int b = rb + tid;
        float2* oa = (float2*)(outF + (size_t)b * 6);
        oa[0] = make_float2(av[0], av[1]);
        oa[1] = make_float2(av[2], av[3]);
        oa[2] = make_float2(av[4], av[5]);
        float2* orw = (float2*)(outF + (size_t)B_TOTAL * 6 + (size_t)b * 6);
        orw[0] = make_float2(rawv[0], rawv[1]);
        orw[1] = make_float2(rawv[2], rawv[3]);
        orw[2] = make_float2(rawv[4], rawv[5]);
    }
}

extern "C" void kernel_launch(void* const* d_in, const int* in_sizes, int n_in,
                              void* d_out, int out_size, void* d_ws, size_t ws_size,
                              hipStream_t stream) {
    uint16_t* wsb = (uint16_t*)d_ws;
    convert_kernel<<<(CONV_TOT + 255) / 256, 256, 0, stream>>>(
        d_in[1], d_in[2], d_in[3], d_in[4], d_in[5], d_in[6], d_in[7], d_in[8],
        d_in[9], d_in[10], wsb);
    chambers_mfma<<<B_TOTAL / 64, 256, 0, stream>>>(
        d_in[0], wsb, (const uint32_t*)d_in[9], (float*)d_out);
}